// Round 9
// baseline (1148.425 us; speedup 1.0000x reference)
//
#include <hip/hip_runtime.h>
#include <cstddef>

#define N_NODES 16384
#define N_GRAPHS 64
#define NPG 256
#define F_IN 128
#define E_DIM 256
#define N_HEADS 8
#define DH 32
#define MLP 1024
#define N_LAYERS 4
#define N_CLASSES 10
#define N_EDGES 262144
#define S_LEN 257
#define M_ROWS (N_GRAPHS * S_LEN)   // 16448
#define M_PAD 16512                 // 129 * 128
#define LN_EPS 1e-5f

typedef __attribute__((ext_vector_type(8))) short bf16x8;   // 8 bf16 in 4 VGPRs
typedef __attribute__((ext_vector_type(4))) float f32x4;

__device__ inline unsigned short f2b1(float f) {
    unsigned u = __float_as_uint(f);
    unsigned r = (u + 0x7fffu + ((u >> 16) & 1u)) >> 16;
    return (unsigned short)r;
}

#define GLOBAL_LOAD_LDS16(g, l) \
    __builtin_amdgcn_global_load_lds((__attribute__((address_space(1))) const void*)(g), \
                                     (__attribute__((address_space(3))) void*)(l), 16, 0, 0)

// ---------------- fp32 -> bf16 conversion, all 7 weight regions in one dispatch -----
struct F2BJobs {
    const float* src[7];
    unsigned short* dst[7];
    int n4[7];
};
__global__ __launch_bounds__(256) void f2b_all(F2BJobs jobs) {
#pragma unroll 1
    for (int r = 0; r < 7; ++r) {
        const float4* s = (const float4*)jobs.src[r];
        ushort4* d = (ushort4*)jobs.dst[r];
        const int n4 = jobs.n4[r];
        for (int i = blockIdx.x * 256 + threadIdx.x; i < n4; i += gridDim.x * 256) {
            float4 v = s[i];
            ushort4 o;
            o.x = f2b1(v.x); o.y = f2b1(v.y); o.z = f2b1(v.z); o.w = f2b1(v.w);
            d[i] = o;
        }
    }
}

// ---------------- MFMA GEMM: C(M,N) = A(M,K) @ W(N,K)^T (+bias)(+add)(relu?) --------
// 128x128 tile, BK=32, double-buffered LDS, one barrier per k-step.
__global__ __launch_bounds__(256) void gemm_mfma(
    const unsigned short* __restrict__ A, const unsigned short* __restrict__ W,
    const float* __restrict__ bias, const float* __restrict__ add,
    float* __restrict__ outF, unsigned short* __restrict__ outB,
    int M, int N, int K, int relu)
{
    __shared__ __align__(16) unsigned short As0[128 * 32], As1[128 * 32];
    __shared__ __align__(16) unsigned short Bs0[128 * 32], Bs1[128 * 32];
    const int tid = threadIdx.x;
    const int wave = tid >> 6;
    const int lane = tid & 63;
    const int bm = blockIdx.y * 128;
    const int bn = blockIdx.x * 128;

    const int srow = (lane >> 2);
    const int scol = (lane & 3) * 8;
    const size_t a_r0 = (size_t)(bm + wave * 16 + srow) * K + scol;
    const size_t b_r0 = (size_t)(bn + wave * 16 + srow) * K + scol;

    const int wm = (wave & 1) * 64;
    const int wn = (wave >> 1) * 64;
    const int fr = lane & 15;
    const int fk = (lane >> 4) * 8;

    f32x4 acc[4][4];
#pragma unroll
    for (int i = 0; i < 4; ++i)
#pragma unroll
        for (int j = 0; j < 4; ++j)
            acc[i][j] = (f32x4){0.f, 0.f, 0.f, 0.f};

    auto stage = [&](unsigned short* Asb, unsigned short* Bsb, int k0) {
        GLOBAL_LOAD_LDS16(A + a_r0 + k0, Asb + wave * 512);
        GLOBAL_LOAD_LDS16(A + a_r0 + (size_t)64 * K + k0, Asb + (wave + 4) * 512);
        GLOBAL_LOAD_LDS16(W + b_r0 + k0, Bsb + wave * 512);
        GLOBAL_LOAD_LDS16(W + b_r0 + (size_t)64 * K + k0, Bsb + (wave + 4) * 512);
    };
    auto compute = [&](const unsigned short* Asb, const unsigned short* Bsb) {
        bf16x8 a[4], b[4];
#pragma unroll
        for (int i = 0; i < 4; ++i)
            a[i] = *(const bf16x8*)(Asb + (wm + i * 16 + fr) * 32 + fk);
#pragma unroll
        for (int j = 0; j < 4; ++j)
            b[j] = *(const bf16x8*)(Bsb + (wn + j * 16 + fr) * 32 + fk);
#pragma unroll
        for (int i = 0; i < 4; ++i)
#pragma unroll
            for (int j = 0; j < 4; ++j)
                acc[i][j] = __builtin_amdgcn_mfma_f32_16x16x32_bf16(a[i], b[j], acc[i][j], 0, 0, 0);
    };

    stage(As0, Bs0, 0);
    for (int k0 = 0; k0 < K; k0 += 64) {
        __syncthreads();
        if (k0 + 32 < K) stage(As1, Bs1, k0 + 32);
        compute(As0, Bs0);
        __syncthreads();
        if (k0 + 64 < K) stage(As0, Bs0, k0 + 64);
        compute(As1, Bs1);
    }

    const int er = (lane >> 4) * 4;
    const int ec = lane & 15;
#pragma unroll
    for (int j = 0; j < 4; ++j) {
        const int col = bn + wn + j * 16 + ec;
        const float bs = bias ? bias[col] : 0.f;
#pragma unroll
        for (int i = 0; i < 4; ++i) {
#pragma unroll
            for (int r = 0; r < 4; ++r) {
                const int row = bm + wm + i * 16 + er + r;
                float v = acc[i][j][r] + bs;
                if (add)  v += add[(size_t)row * N + col];
                if (relu) v = fmaxf(v, 0.f);
                if (outF) outF[(size_t)row * N + col] = v;
                if (outB) outB[(size_t)row * N + col] = f2b1(v);
            }
        }
    }
}

// ---------------- fused GEMM + residual + LayerNorm (N = 256), reg-pipelined --------
// 32x256 tile, grid M_PAD/32 = 516 (2 blocks/CU). Wave w: rows (w>>1)*16..+15,
// col-half (w&1)*128. A and B fragments load DIRECTLY global->VGPR (both are
// contiguous bf16x8 segments in the MFMA operand layouts) through a depth-4
// register ring -> no LDS in the K-loop, no global_load_lds/ds_read hazard
// (R8 post-mortem: that pairing races without a barrier). LN via in-wave shfl
// + cross-wave LDS exchange at the end.
template<int K>
__global__ __launch_bounds__(256, 2) void gemm_ln_t(
    const unsigned short* __restrict__ A, const unsigned short* __restrict__ W,
    const float* __restrict__ bias, const float* __restrict__ g,
    const float* __restrict__ beta,
    float* __restrict__ h, unsigned short* __restrict__ hb)
{
    constexpr int NSTEP = K / 32;
    constexpr int RD = (NSTEP < 4) ? NSTEP : 4;   // ring depth / prefetch distance
    __shared__ float red[2][2][16][2];   // [rgrp][ch][row16][{s1,s2}]
    const int tid  = threadIdx.x;
    const int wave = tid >> 6;
    const int lane = tid & 63;
    const int quad = lane >> 4;
    const int l16  = lane & 15;
    const int rgrp = wave >> 1;
    const int ch   = wave & 1;
    const int bm   = blockIdx.x * 32;

    // per-lane base pointers (A-operand layout: lane holds A[m=l16][k=quad*8+j])
    const unsigned short* Ap = A + (size_t)(bm + rgrp * 16 + l16) * K + quad * 8;
    const unsigned short* Bp[8];
#pragma unroll
    for (int j = 0; j < 8; ++j)
        Bp[j] = W + (size_t)(ch * 128 + j * 16 + l16) * K + quad * 8;

    f32x4 acc[8];
#pragma unroll
    for (int j = 0; j < 8; ++j) acc[j] = (f32x4){0.f, 0.f, 0.f, 0.f};

    bf16x8 areg[RD];
    bf16x8 breg[RD][8];
#pragma unroll
    for (int p = 0; p < RD; ++p) {
        areg[p] = *(const bf16x8*)(Ap + p * 32);
#pragma unroll
        for (int j = 0; j < 8; ++j)
            breg[p][j] = *(const bf16x8*)(Bp[j] + p * 32);
    }

#pragma unroll
    for (int s = 0; s < NSTEP; ++s) {
        const int sl = s % RD;
#pragma unroll
        for (int j = 0; j < 8; ++j)
            acc[j] = __builtin_amdgcn_mfma_f32_16x16x32_bf16(areg[sl], breg[sl][j], acc[j], 0, 0, 0);
        if (s + RD < NSTEP) {
            areg[sl] = *(const bf16x8*)(Ap + (s + RD) * 32);
#pragma unroll
            for (int j = 0; j < 8; ++j)
                breg[sl][j] = *(const bf16x8*)(Bp[j] + (s + RD) * 32);
        }
    }

    // ---- epilogue: bias + residual, cross-wave LN, write h fp32 + hb bf16 ----
    float gv[8], bv[8], biasv[8];
#pragma unroll
    for (int j = 0; j < 8; ++j) {
        const int col = ch * 128 + j * 16 + l16;
        gv[j] = g[col]; bv[j] = beta[col]; biasv[j] = bias[col];
    }
    float v[4][8];
#pragma unroll
    for (int r = 0; r < 4; ++r) {
        const int row = bm + rgrp * 16 + quad * 4 + r;
        float s1 = 0.f, s2 = 0.f;
#pragma unroll
        for (int j = 0; j < 8; ++j) {
            const int col = ch * 128 + j * 16 + l16;
            float t = acc[j][r] + biasv[j] + h[(size_t)row * E_DIM + col];
            v[r][j] = t; s1 += t; s2 += t * t;
        }
        s1 += __shfl_xor(s1, 1, 64); s2 += __shfl_xor(s2, 1, 64);
        s1 += __shfl_xor(s1, 2, 64); s2 += __shfl_xor(s2, 2, 64);
        s1 += __shfl_xor(s1, 4, 64); s2 += __shfl_xor(s2, 4, 64);
        s1 += __shfl_xor(s1, 8, 64); s2 += __shfl_xor(s2, 8, 64);
        if (l16 == 0) { red[rgrp][ch][quad * 4 + r][0] = s1; red[rgrp][ch][quad * 4 + r][1] = s2; }
    }
    __syncthreads();
#pragma unroll
    for (int r = 0; r < 4; ++r) {
        const int row = bm + rgrp * 16 + quad * 4 + r;
        const float t1 = red[rgrp][0][quad * 4 + r][0] + red[rgrp][1][quad * 4 + r][0];
        const float t2 = red[rgrp][0][quad * 4 + r][1] + red[rgrp][1][quad * 4 + r][1];
        const float mu = t1 * (1.f / 256.f);
        const float var = t2 * (1.f / 256.f) - mu * mu;
        const float rstd = rsqrtf(var + LN_EPS);
#pragma unroll
        for (int j = 0; j < 8; ++j) {
            const int col = ch * 128 + j * 16 + l16;
            float o = (v[r][j] - mu) * rstd * gv[j] + bv[j];
            h[(size_t)row * E_DIM + col] = o;
            hb[(size_t)row * E_DIM + col] = f2b1(o);
        }
    }
}

// ---------------- GCN: CSR build + gather ----------------
__global__ void deg_count(const int* __restrict__ ei, float* __restrict__ deg) {
    int e = blockIdx.x * blockDim.x + threadIdx.x;
    if (e < N_EDGES) atomicAdd(&deg[ei[N_EDGES + e]], 1.0f);
}

__global__ __launch_bounds__(1024) void scan_deg(const float* __restrict__ deg,
                                                 int* __restrict__ row_start) {
    __shared__ int lds[1024];
    const int t = threadIdx.x;
    const int base = t * 16;
    int loc[16];
    int s = 0;
#pragma unroll
    for (int i = 0; i < 16; ++i) { loc[i] = s; s += (int)deg[base + i]; }
    lds[t] = s;
    __syncthreads();
    for (int off = 1; off < 1024; off <<= 1) {
        int v = lds[t];
        int u = (t >= off) ? lds[t - off] : 0;
        __syncthreads();
        lds[t] = v + u;
        __syncthreads();
    }
    const int excl = (t == 0) ? 0 : lds[t - 1];
#pragma unroll
    for (int i = 0; i < 16; ++i) row_start[base + i] = excl + loc[i];
    if (t == 1023) row_start[16384] = lds[1023];
}

__global__ void make_dinv(float* __restrict__ deg) {
    int i = blockIdx.x * blockDim.x + threadIdx.x;
    if (i < N_NODES) deg[i] = rsqrtf(deg[i] + 1.0f);  // +1 self loop
}

__global__ void scatter_edges(const int* __restrict__ ei, const float* __restrict__ dinv,
                              const int* __restrict__ row_start, int* __restrict__ cursor,
                              int* __restrict__ esrc, float* __restrict__ enrm) {
    int e = blockIdx.x * 256 + threadIdx.x;
    if (e < N_EDGES) {
        int r = ei[e], c = ei[N_EDGES + e];
        int slot = atomicAdd(&cursor[c], 1);
        int p = row_start[c] + slot;
        esrc[p] = r;
        enrm[p] = dinv[r] * dinv[c];
    }
}

__global__ __launch_bounds__(256) void gcn_gather(
    const float* __restrict__ xw, const int* __restrict__ row_start,
    const int* __restrict__ esrc, const float* __restrict__ enrm,
    const float* __restrict__ dinv, const float* __restrict__ bias,
    unsigned short* __restrict__ aggb) {
    const int n = blockIdx.x * 4 + (threadIdx.x >> 6);
    const int t = threadIdx.x & 63;  // float2 per lane
    const int e0 = row_start[n], e1 = row_start[n + 1];
    float ax = 0.f, ay = 0.f;
    for (int e = e0; e < e1; ++e) {
        int s = esrc[e];       // wave-uniform -> s_load
        float w = enrm[e];     // wave-uniform -> s_load
        float2 v = ((const float2*)(xw + (size_t)s * F_IN))[t];
        ax += w * v.x; ay += w * v.y;
    }
    const float di = dinv[n];
    const float w0 = di * di;
    float2 vs = ((const float2*)(xw + (size_t)n * F_IN))[t];
    ax += w0 * vs.x; ay += w0 * vs.y;
    float2 b2 = ((const float2*)bias)[t];
    ushort2 o;
    o.x = f2b1(fmaxf(ax + b2.x, 0.f));
    o.y = f2b1(fmaxf(ay + b2.y, 0.f));
    ((ushort2*)(aggb + (size_t)n * F_IN))[t] = o;
}

// ---------------- h assembly ----------------
__global__ void assemble_h(const float* __restrict__ emb, const float* __restrict__ cls,
                           float* __restrict__ h, unsigned short* __restrict__ hb) {
    int row = blockIdx.x;            // 0..16447
    int f = threadIdx.x;             // 256
    int g = row / S_LEN, s = row % S_LEN;
    float v = (s == 0) ? cls[f] : emb[((size_t)g * NPG + (s - 1)) * E_DIM + f];
    h[(size_t)row * E_DIM + f] = v;
    hb[(size_t)row * E_DIM + f] = f2b1(v);
}

// ---------------- MFMA flash attention: one workgroup per (graph, head) ------------
__global__ __launch_bounds__(256) void attn_mfma(const unsigned short* __restrict__ qkvb,
                                                 unsigned short* __restrict__ ob) {
    const int g  = blockIdx.x >> 3;
    const int hh = blockIdx.x & 7;
    __shared__ __align__(16) unsigned short Ks[272 * 32];      // K [s][d]
    __shared__ __align__(16) unsigned short VT[32 * 288];      // V^T [d][s]
    __shared__ __align__(16) unsigned short Ps[4 * 16 * 288];  // per-wave P tile
    const int tid  = threadIdx.x;
    const int wave = tid >> 6;
    const int lane = tid & 63;
    const int quad = lane >> 4;
    const int l16  = lane & 15;
    const size_t grow0 = (size_t)g * S_LEN;

    for (int s = tid; s < 272; s += 256) {
        uint4* dst = (uint4*)&Ks[s * 32];
        if (s < S_LEN) {
            const uint4* src = (const uint4*)(qkvb + (grow0 + s) * 768 + 256 + hh * 32);
            dst[0] = src[0]; dst[1] = src[1]; dst[2] = src[2]; dst[3] = src[3];
        } else {
            uint4 z = {0u, 0u, 0u, 0u};
            dst[0] = z; dst[1] = z; dst[2] = z; dst[3] = z;
        }
    }
    for (int s = tid; s < 288; s += 256) {
        unsigned short t[32];
        if (s < S_LEN) {
            const uint4* src = (const uint4*)(qkvb + (grow0 + s) * 768 + 512 + hh * 32);
            ((uint4*)t)[0] = src[0]; ((uint4*)t)[1] = src[1];
            ((uint4*)t)[2] = src[2]; ((uint4*)t)[3] = src[3];
        } else {
#pragma unroll
            for (int d = 0; d < 32; ++d) t[d] = 0;
        }
#pragma unroll
        for (int d = 0; d < 32; ++d) VT[d * 288 + s] = t[d];
    }
    unsigned short* Pw = &Ps[wave * 16 * 288];
    for (int i = lane; i < 256; i += 64)
        Pw[(i >> 4) * 288 + 272 + (i & 15)] = 0;
    __syncthreads();

    const float scale = 0.17677669529663687f;  // 1/sqrt(32)
    for (int qt = wave; qt < 17; qt += 4) {
        const int qrow_l = qt * 16 + l16;
        bf16x8 aq = *(const bf16x8*)(qkvb + (grow0 + qrow_l) * 768 + hh * 32 + quad * 8);

        f32x4 sc[17];
#pragma unroll
        for (int kt = 0; kt < 17; ++kt) {
            bf16x8 bk = *(const bf16x8*)&Ks[(kt * 16 + l16) * 32 + quad * 8];
            f32x4 z = (f32x4){0.f, 0.f, 0.f, 0.f};
            sc[kt] = __builtin_amdgcn_mfma_f32_16x16x32_bf16(aq, bk, z, 0, 0, 0);
        }

        float lsum[4] = {0.f, 0.f, 0.f, 0.f};
#pragma unroll
        for (int kt = 0; kt < 17; ++kt) {
#pragma unroll
            for (int r = 0; r < 4; ++r) {
                float p = __expf(sc[kt][r] * scale);
                if (kt == 16 && l16 != 0) p = 0.f;
                lsum[r] += p;
                Pw[(quad * 4 + r) * 288 + kt * 16 + l16] = f2b1(p);
            }
        }
#pragma unroll
        for (int r = 0; r < 4; ++r) {
            float s = lsum[r];
            s += __shfl_xor(s, 1, 64);
            s += __shfl_xor(s, 2, 64);
            s += __shfl_xor(s, 4, 64);
            s += __shfl_xor(s, 8, 64);
            lsum[r] = s;
        }

        f32x4 o0 = (f32x4){0.f, 0.f, 0.f, 0.f};
        f32x4 o1 = (f32x4){0.f, 0.f, 0.f, 0.f};
#pragma unroll
        for (int c = 0; c < 9; ++c) {
            bf16x8 ap  = *(const bf16x8*)&Pw[l16 * 288 + c * 32 + quad * 8];
            bf16x8 bv0 = *(const bf16x8*)&VT[l16 * 288 + c * 32 + quad * 8];
            bf16x8 bv1 = *(const bf16x8*)&VT[(16 + l16) * 288 + c * 32 + quad * 8];
            o0 = __builtin_amdgcn_mfma_f32_16x16x32_bf16(ap, bv0, o0, 0, 0, 0);
            o1 = __builtin_amdgcn_mfma_f32_16x16x32_bf16(ap, bv1, o1, 0, 0, 0);
        }

#pragma unroll
        for (int r = 0; r < 4; ++r) {
            int row_l = qt * 16 + quad * 4 + r;
            if (row_l < S_LEN) {
                float inv = 1.f / lsum[r];
                size_t orow = (grow0 + row_l) * E_DIM + hh * 32;
                ob[orow + l16]      = f2b1(o0[r] * inv);
                ob[orow + 16 + l16] = f2b1(o1[r] * inv);
            }
        }
    }
}

// ---------------- final classifier ----------------
__global__ void fc_kernel(const float* __restrict__ h, const float* __restrict__ w,
                          const float* __restrict__ b, float* __restrict__ out) {
    int g = blockIdx.x;
    __shared__ float row[E_DIM];
    int t = threadIdx.x;
    row[t] = h[(size_t)g * S_LEN * E_DIM + t];
    __syncthreads();
    if (t < N_CLASSES) {
        float s = 0.f;
        for (int j = 0; j < E_DIM; ++j) s += row[j] * w[t * E_DIM + j];
        out[g * N_CLASSES + t] = s + b[t];
    }
}

extern "C" void kernel_launch(void* const* d_in, const int* in_sizes, int n_in,
                              void* d_out, int out_size, void* d_ws, size_t ws_size,
                              hipStream_t stream) {
    const float* x       = (const float*)d_in[0];
    const int*   edgei   = (const int*)  d_in[1];
    const float* pos_enc = (const float*)d_in[3];
    const float* gcn_w   = (const float*)d_in[4];
    const float* gcn_b   = (const float*)d_in[5];
    const float* cls     = (const float*)d_in[6];
    const float* emb_w   = (const float*)d_in[7];
    const float* emb_b   = (const float*)d_in[8];
    const float* in_w    = (const float*)d_in[9];
    const float* in_b    = (const float*)d_in[10];
    const float* out_w   = (const float*)d_in[11];
    const float* out_b   = (const float*)d_in[12];
    const float* lin1_w  = (const float*)d_in[13];
    const float* lin1_b  = (const float*)d_in[14];
    const float* lin2_w  = (const float*)d_in[15];
    const float* lin2_b  = (const float*)d_in[16];
    const float* ln1_g   = (const float*)d_in[17];
    const float* ln1_be  = (const float*)d_in[18];
    const float* ln2_g   = (const float*)d_in[19];
    const float* ln2_be  = (const float*)d_in[20];
    const float* fc_w    = (const float*)d_in[21];
    const float* fc_b    = (const float*)d_in[22];
    float* out = (float*)d_out;

    // ---- workspace layout ----
    float* ws = (float*)d_ws;
    float* h    = ws;                                  // M_PAD*256 fp32
    float* qkv  = h   + (size_t)M_PAD * E_DIM;         // M_PAD*768 fp32 region
    float* xw   = qkv + (size_t)M_PAD * 768;           // 16384*128 fp32
    float* deg  = xw  + (size_t)N_NODES * F_IN;        // 16384 f
    int*   cursor    = (int*)(deg + N_NODES);          // 16384 i (zeroed with deg)
    int*   row_start = cursor + N_NODES;               // 16385 i
    int*   esrc      = row_start + N_NODES + 1;        // 262144 i
    float* enrm      = (float*)(esrc + N_EDGES);       // 262144 f
    unsigned short* ub     = (unsigned short*)(enrm + N_EDGES);
    unsigned short* hb     = ub;                                  // M_PAD*256
    unsigned short* attnob = hb     + (size_t)M_PAD * E_DIM;      // M_PAD*256
    unsigned short* fbufb  = attnob + (size_t)M_PAD * E_DIM;      // M_PAD*1024
    unsigned short* xb     = fbufb  + (size_t)M_PAD * MLP;        // 16384*128
    unsigned short* aggb   = xb     + (size_t)N_NODES * F_IN;     // 16384*128
    unsigned short* gcn_wb = aggb   + (size_t)N_NODES * F_IN;     // 128*128
    unsigned short* emb_wb = gcn_wb + (size_t)F_IN * F_IN;        // 256*128
    unsigned short* in_wb  = emb_wb + (size_t)E_DIM * F_IN;       // 4*768*256
    unsigned short* out_wb = in_wb  + (size_t)N_LAYERS * 768 * E_DIM;
    unsigned short* lin1_wb= out_wb + (size_t)N_LAYERS * E_DIM * E_DIM;
    unsigned short* lin2_wb= lin1_wb+ (size_t)N_LAYERS * MLP * E_DIM;
    float* emb_out = qkv;                        // alias (pre-loop)
    unsigned short* qkvb = (unsigned short*)qkv; // alias (in-loop, bf16)

    // ---- all weight/input conversions in one dispatch ----
    F2BJobs jobs;
    jobs.src[0] = x;      jobs.dst[0] = xb;      jobs.n4[0] = N_NODES * F_IN / 4;
    jobs.src[1] = gcn_w;  jobs.dst[1] = gcn_wb;  jobs.n4[1] = F_IN * F_IN / 4;
    jobs.src[2] = emb_w;  jobs.dst[2] = emb_wb;  jobs.n4[2] = E_DIM * F_IN / 4;
    jobs.src[3] = in_w;   jobs.dst[3] = in_wb;   jobs.n4[3] = N_LAYERS * 768 * E_DIM / 4;
    jobs.src[4] = out_w;  jobs.dst[4] = out_wb;  jobs.n4[4] = N_LAYERS * E_DIM * E_DIM / 4;
    jobs.src[5] = lin1_w; jobs.dst[5] = lin1_wb; jobs.n4[5] = N_LAYERS * MLP * E_DIM / 4;
    jobs.src[6] = lin2_w; jobs.dst[6] = lin2_wb; jobs.n4[6] = N_LAYERS * E_DIM * MLP / 4;
    f2b_all<<<1024, 256, 0, stream>>>(jobs);

    // ---- GCN: CSR build + gemm + gather ----
    hipMemsetAsync(deg, 0, 2 * N_NODES * sizeof(float), stream);  // deg + cursor
    deg_count<<<(N_EDGES + 255) / 256, 256, 0, stream>>>(edgei, deg);
    scan_deg<<<1, 1024, 0, stream>>>(deg, row_start);
    make_dinv<<<(N_NODES + 255) / 256, 256, 0, stream>>>(deg);
    gemm_mfma<<<dim3(F_IN / 128, N_NODES / 128), 256, 0, stream>>>(
        xb, gcn_wb, nullptr, nullptr, xw, nullptr, N_NODES, F_IN, F_IN, 0);
    scatter_edges<<<(N_EDGES + 255) / 256, 256, 0, stream>>>(edgei, deg, row_start, cursor, esrc, enrm);
    gcn_gather<<<N_NODES / 4, 256, 0, stream>>>(xw, row_start, esrc, enrm, deg, gcn_b, aggb);

    // ---- embedding + pos_enc ----
    gemm_mfma<<<dim3(E_DIM / 128, N_NODES / 128), 256, 0, stream>>>(
        aggb, emb_wb, emb_b, pos_enc, emb_out, nullptr, N_NODES, E_DIM, F_IN, 0);
    assemble_h<<<M_ROWS, E_DIM, 0, stream>>>(emb_out, cls, h, hb);

    // ---- transformer layers ----
    for (int l = 0; l < N_LAYERS; ++l) {
        gemm_mfma<<<dim3(768 / 128, M_PAD / 128), 256, 0, stream>>>(
            hb, in_wb + (size_t)l * 768 * E_DIM, in_b + (size_t)l * 768, nullptr,
            nullptr, qkvb, M_PAD, 768, E_DIM, 0);
        attn_mfma<<<N_GRAPHS * N_HEADS, 256, 0, stream>>>(qkvb, attnob);
        gemm_ln_t<E_DIM><<<M_PAD / 32, 256, 0, stream>>>(
            attnob, out_wb + (size_t)l * E_DIM * E_DIM, out_b + (size_t)l * E_DIM,
            ln1_g + l * E_DIM, ln1_be + l * E_DIM, h, hb);
        gemm_mfma<<<dim3(MLP / 128, M_PAD / 128), 256, 0, stream>>>(
            hb, lin1_wb + (size_t)l * MLP * E_DIM, lin1_b + (size_t)l * MLP, nullptr,
            nullptr, fbufb, M_PAD, MLP, E_DIM, 1);
        gemm_ln_t<MLP><<<M_PAD / 32, 256, 0, stream>>>(
            fbufb, lin2_wb + (size_t)l * MLP * E_DIM, lin2_b + (size_t)l * E_DIM,
            ln2_g + l * E_DIM, ln2_be + l * E_DIM, h, hb);
    }

    // ---- classifier on cls tokens ----
    fc_kernel<<<N_GRAPHS, E_DIM, 0, stream>>>(h, fc_w, fc_b, out);
}

// Round 10
// 866.794 us; speedup vs baseline: 1.3249x; 1.3249x over previous
//
#include <hip/hip_runtime.h>
#include <cstddef>

#define N_NODES 16384
#define N_GRAPHS 64
#define NPG 256
#define F_IN 128
#define E_DIM 256
#define N_HEADS 8
#define DH 32
#define MLP 1024
#define N_LAYERS 4
#define N_CLASSES 10
#define N_EDGES 262144
#define S_LEN 257
#define M_ROWS (N_GRAPHS * S_LEN)   // 16448
#define M_PAD 16512                 // 129 * 128
#define LN_EPS 1e-5f

typedef __attribute__((ext_vector_type(8))) short bf16x8;   // 8 bf16 in 4 VGPRs
typedef __attribute__((ext_vector_type(4))) float f32x4;

__device__ inline unsigned short f2b1(float f) {
    unsigned u = __float_as_uint(f);
    unsigned r = (u + 0x7fffu + ((u >> 16) & 1u)) >> 16;
    return (unsigned short)r;
}

#define GLOBAL_LOAD_LDS16(g, l) \
    __builtin_amdgcn_global_load_lds((__attribute__((address_space(1))) const void*)(g), \
                                     (__attribute__((address_space(3))) void*)(l), 16, 0, 0)

// ---------------- fp32 -> bf16 conversion, all 7 weight regions in one dispatch -----
struct F2BJobs {
    const float* src[7];
    unsigned short* dst[7];
    int n4[7];
};
__global__ __launch_bounds__(256) void f2b_all(F2BJobs jobs) {
#pragma unroll 1
    for (int r = 0; r < 7; ++r) {
        const float4* s = (const float4*)jobs.src[r];
        ushort4* d = (ushort4*)jobs.dst[r];
        const int n4 = jobs.n4[r];
        for (int i = blockIdx.x * 256 + threadIdx.x; i < n4; i += gridDim.x * 256) {
            float4 v = s[i];
            ushort4 o;
            o.x = f2b1(v.x); o.y = f2b1(v.y); o.z = f2b1(v.z); o.w = f2b1(v.w);
            d[i] = o;
        }
    }
}

// ---------------- MFMA GEMM: C(M,N) = A(M,K) @ W(N,K)^T (+bias)(+add)(relu?) --------
// 128x128 tile, BK=32, double-buffered LDS, one barrier per k-step.
__global__ __launch_bounds__(256) void gemm_mfma(
    const unsigned short* __restrict__ A, const unsigned short* __restrict__ W,
    const float* __restrict__ bias, const float* __restrict__ add,
    float* __restrict__ outF, unsigned short* __restrict__ outB,
    int M, int N, int K, int relu)
{
    __shared__ __align__(16) unsigned short As0[128 * 32], As1[128 * 32];
    __shared__ __align__(16) unsigned short Bs0[128 * 32], Bs1[128 * 32];
    const int tid = threadIdx.x;
    const int wave = tid >> 6;
    const int lane = tid & 63;
    const int bm = blockIdx.y * 128;
    const int bn = blockIdx.x * 128;

    const int srow = (lane >> 2);
    const int scol = (lane & 3) * 8;
    const size_t a_r0 = (size_t)(bm + wave * 16 + srow) * K + scol;
    const size_t b_r0 = (size_t)(bn + wave * 16 + srow) * K + scol;

    const int wm = (wave & 1) * 64;
    const int wn = (wave >> 1) * 64;
    const int fr = lane & 15;
    const int fk = (lane >> 4) * 8;

    f32x4 acc[4][4];
#pragma unroll
    for (int i = 0; i < 4; ++i)
#pragma unroll
        for (int j = 0; j < 4; ++j)
            acc[i][j] = (f32x4){0.f, 0.f, 0.f, 0.f};

    auto stage = [&](unsigned short* Asb, unsigned short* Bsb, int k0) {
        GLOBAL_LOAD_LDS16(A + a_r0 + k0, Asb + wave * 512);
        GLOBAL_LOAD_LDS16(A + a_r0 + (size_t)64 * K + k0, Asb + (wave + 4) * 512);
        GLOBAL_LOAD_LDS16(W + b_r0 + k0, Bsb + wave * 512);
        GLOBAL_LOAD_LDS16(W + b_r0 + (size_t)64 * K + k0, Bsb + (wave + 4) * 512);
    };
    auto compute = [&](const unsigned short* Asb, const unsigned short* Bsb) {
        bf16x8 a[4], b[4];
#pragma unroll
        for (int i = 0; i < 4; ++i)
            a[i] = *(const bf16x8*)(Asb + (wm + i * 16 + fr) * 32 + fk);
#pragma unroll
        for (int j = 0; j < 4; ++j)
            b[j] = *(const bf16x8*)(Bsb + (wn + j * 16 + fr) * 32 + fk);
#pragma unroll
        for (int i = 0; i < 4; ++i)
#pragma unroll
            for (int j = 0; j < 4; ++j)
                acc[i][j] = __builtin_amdgcn_mfma_f32_16x16x32_bf16(a[i], b[j], acc[i][j], 0, 0, 0);
    };

    stage(As0, Bs0, 0);
    for (int k0 = 0; k0 < K; k0 += 64) {
        __syncthreads();
        if (k0 + 32 < K) stage(As1, Bs1, k0 + 32);
        compute(As0, Bs0);
        __syncthreads();
        if (k0 + 64 < K) stage(As0, Bs0, k0 + 64);
        compute(As1, Bs1);
    }

    const int er = (lane >> 4) * 4;
    const int ec = lane & 15;
#pragma unroll
    for (int j = 0; j < 4; ++j) {
        const int col = bn + wn + j * 16 + ec;
        const float bs = bias ? bias[col] : 0.f;
#pragma unroll
        for (int i = 0; i < 4; ++i) {
#pragma unroll
            for (int r = 0; r < 4; ++r) {
                const int row = bm + wm + i * 16 + er + r;
                float v = acc[i][j][r] + bs;
                if (add)  v += add[(size_t)row * N + col];
                if (relu) v = fmaxf(v, 0.f);
                if (outF) outF[(size_t)row * N + col] = v;
                if (outB) outB[(size_t)row * N + col] = f2b1(v);
            }
        }
    }
}

// ---------------- fused GEMM + residual + LayerNorm (N = 256), BK=64 + swizzle ------
// 32x256 tile, grid M_PAD/32 = 516 (2 blocks/CU, LDS 72 KB). Wave w: rows
// (w>>1)*16..+15, col-half (w&1)*128. BK=64 halves the barrier count vs BK=32
// (the R6/R7 floor was exposed-latency-per-barrier). Rows are 128 B at BK=64, so
// the natural layout would hit only 16/32 banks; 16B-chunk XOR swizzle
// (chunk' = chunk ^ (row&7)) applied in BOTH the DMA fetch address and the
// ds_read address restores perfect bank balance while keeping the global fetch
// coalesced (each row still = 2 full 64B lines) and the LDS dst contiguous.
template<int K>
__global__ __launch_bounds__(256, 2) void gemm_ln_t(
    const unsigned short* __restrict__ A, const unsigned short* __restrict__ W,
    const float* __restrict__ bias, const float* __restrict__ g,
    const float* __restrict__ beta,
    float* __restrict__ h, unsigned short* __restrict__ hb)
{
    constexpr int NSTEP = K / 64;
    __shared__ __align__(16) unsigned short As0[32 * 64], As1[32 * 64];     // 4 KB each
    __shared__ __align__(16) unsigned short Bs0[256 * 64], Bs1[256 * 64];   // 32 KB each
    __shared__ float red[2][2][16][2];   // [rgrp][ch][row16][{s1,s2}]
    const int tid  = threadIdx.x;
    const int wave = tid >> 6;
    const int lane = tid & 63;
    const int quad = lane >> 4;
    const int l16  = lane & 15;
    const int rgrp = wave >> 1;
    const int ch   = wave & 1;
    const int bm   = blockIdx.x * 32;

    // staging: issue covers 8 rows x 8 chunks(16B). lane: r8 = lane>>3, c = lane&7.
    // fetch global chunk (c ^ r8) so LDS slot c of row r holds global chunk c^(r&7).
    const int r8 = lane >> 3;
    const int cs = (lane & 7) ^ r8;          // swizzled chunk to fetch
    const size_t a_g0 = (size_t)(bm + wave * 8 + r8) * K + cs * 8;

    auto stage = [&](unsigned short* Asb, unsigned short* Bsb, int k0) {
        GLOBAL_LOAD_LDS16(A + a_g0 + k0, Asb + wave * 512);
#pragma unroll
        for (int it = 0; it < 8; ++it)
            GLOBAL_LOAD_LDS16(W + (size_t)(it * 32 + wave * 8 + r8) * K + k0 + cs * 8,
                              Bsb + it * 2048 + wave * 512);
    };

    f32x4 acc[8];
#pragma unroll
    for (int j = 0; j < 8; ++j) acc[j] = (f32x4){0.f, 0.f, 0.f, 0.f};

    const int sw = l16 & 7;
    auto compute = [&](const unsigned short* Asb, const unsigned short* Bsb) {
#pragma unroll
        for (int kk = 0; kk < 2; ++kk) {
            const int ca = ((kk * 4 + quad) ^ sw) * 8;   // swizzled k-offset (shorts)
            bf16x8 a = *(const bf16x8*)(Asb + (rgrp * 16 + l16) * 64 + ca);
#pragma unroll
            for (int j = 0; j < 8; ++j) {
                bf16x8 b = *(const bf16x8*)(Bsb + (ch * 128 + j * 16 + l16) * 64 + ca);
                acc[j] = __builtin_amdgcn_mfma_f32_16x16x32_bf16(a, b, acc[j], 0, 0, 0);
            }
        }
    };

    stage(As0, Bs0, 0);
#pragma unroll
    for (int s = 0; s < NSTEP; ++s) {
        __syncthreads();                                   // drains DMA into current
        if (s + 1 < NSTEP) stage((s & 1) ? As0 : As1, (s & 1) ? Bs0 : Bs1, (s + 1) * 64);
        compute((s & 1) ? As1 : As0, (s & 1) ? Bs1 : Bs0);
    }

    // ---- epilogue: bias + residual, cross-wave LN, write h fp32 + hb bf16 ----
    float gv[8], bv[8], biasv[8];
#pragma unroll
    for (int j = 0; j < 8; ++j) {
        const int col = ch * 128 + j * 16 + l16;
        gv[j] = g[col]; bv[j] = beta[col]; biasv[j] = bias[col];
    }
    float v[4][8];
#pragma unroll
    for (int r = 0; r < 4; ++r) {
        const int row = bm + rgrp * 16 + quad * 4 + r;
        float s1 = 0.f, s2 = 0.f;
#pragma unroll
        for (int j = 0; j < 8; ++j) {
            const int col = ch * 128 + j * 16 + l16;
            float t = acc[j][r] + biasv[j] + h[(size_t)row * E_DIM + col];
            v[r][j] = t; s1 += t; s2 += t * t;
        }
        s1 += __shfl_xor(s1, 1, 64); s2 += __shfl_xor(s2, 1, 64);
        s1 += __shfl_xor(s1, 2, 64); s2 += __shfl_xor(s2, 2, 64);
        s1 += __shfl_xor(s1, 4, 64); s2 += __shfl_xor(s2, 4, 64);
        s1 += __shfl_xor(s1, 8, 64); s2 += __shfl_xor(s2, 8, 64);
        if (l16 == 0) { red[rgrp][ch][quad * 4 + r][0] = s1; red[rgrp][ch][quad * 4 + r][1] = s2; }
    }
    __syncthreads();
#pragma unroll
    for (int r = 0; r < 4; ++r) {
        const int row = bm + rgrp * 16 + quad * 4 + r;
        const float t1 = red[rgrp][0][quad * 4 + r][0] + red[rgrp][1][quad * 4 + r][0];
        const float t2 = red[rgrp][0][quad * 4 + r][1] + red[rgrp][1][quad * 4 + r][1];
        const float mu = t1 * (1.f / 256.f);
        const float var = t2 * (1.f / 256.f) - mu * mu;
        const float rstd = rsqrtf(var + LN_EPS);
#pragma unroll
        for (int j = 0; j < 8; ++j) {
            const int col = ch * 128 + j * 16 + l16;
            float o = (v[r][j] - mu) * rstd * gv[j] + bv[j];
            h[(size_t)row * E_DIM + col] = o;
            hb[(size_t)row * E_DIM + col] = f2b1(o);
        }
    }
}

// ---------------- GCN: CSR build + gather ----------------
__global__ void deg_count(const int* __restrict__ ei, float* __restrict__ deg) {
    int e = blockIdx.x * blockDim.x + threadIdx.x;
    if (e < N_EDGES) atomicAdd(&deg[ei[N_EDGES + e]], 1.0f);
}

__global__ __launch_bounds__(1024) void scan_deg(const float* __restrict__ deg,
                                                 int* __restrict__ row_start) {
    __shared__ int lds[1024];
    const int t = threadIdx.x;
    const int base = t * 16;
    int loc[16];
    int s = 0;
#pragma unroll
    for (int i = 0; i < 16; ++i) { loc[i] = s; s += (int)deg[base + i]; }
    lds[t] = s;
    __syncthreads();
    for (int off = 1; off < 1024; off <<= 1) {
        int v = lds[t];
        int u = (t >= off) ? lds[t - off] : 0;
        __syncthreads();
        lds[t] = v + u;
        __syncthreads();
    }
    const int excl = (t == 0) ? 0 : lds[t - 1];
#pragma unroll
    for (int i = 0; i < 16; ++i) row_start[base + i] = excl + loc[i];
    if (t == 1023) row_start[16384] = lds[1023];
}

__global__ void make_dinv(float* __restrict__ deg) {
    int i = blockIdx.x * blockDim.x + threadIdx.x;
    if (i < N_NODES) deg[i] = rsqrtf(deg[i] + 1.0f);  // +1 self loop
}

__global__ void scatter_edges(const int* __restrict__ ei, const float* __restrict__ dinv,
                              const int* __restrict__ row_start, int* __restrict__ cursor,
                              int* __restrict__ esrc, float* __restrict__ enrm) {
    int e = blockIdx.x * 256 + threadIdx.x;
    if (e < N_EDGES) {
        int r = ei[e], c = ei[N_EDGES + e];
        int slot = atomicAdd(&cursor[c], 1);
        int p = row_start[c] + slot;
        esrc[p] = r;
        enrm[p] = dinv[r] * dinv[c];
    }
}

__global__ __launch_bounds__(256) void gcn_gather(
    const float* __restrict__ xw, const int* __restrict__ row_start,
    const int* __restrict__ esrc, const float* __restrict__ enrm,
    const float* __restrict__ dinv, const float* __restrict__ bias,
    unsigned short* __restrict__ aggb) {
    const int n = blockIdx.x * 4 + (threadIdx.x >> 6);
    const int t = threadIdx.x & 63;  // float2 per lane
    const int e0 = row_start[n], e1 = row_start[n + 1];
    float ax = 0.f, ay = 0.f;
    for (int e = e0; e < e1; ++e) {
        int s = esrc[e];       // wave-uniform -> s_load
        float w = enrm[e];     // wave-uniform -> s_load
        float2 v = ((const float2*)(xw + (size_t)s * F_IN))[t];
        ax += w * v.x; ay += w * v.y;
    }
    const float di = dinv[n];
    const float w0 = di * di;
    float2 vs = ((const float2*)(xw + (size_t)n * F_IN))[t];
    ax += w0 * vs.x; ay += w0 * vs.y;
    float2 b2 = ((const float2*)bias)[t];
    ushort2 o;
    o.x = f2b1(fmaxf(ax + b2.x, 0.f));
    o.y = f2b1(fmaxf(ay + b2.y, 0.f));
    ((ushort2*)(aggb + (size_t)n * F_IN))[t] = o;
}

// ---------------- h assembly ----------------
__global__ void assemble_h(const float* __restrict__ emb, const float* __restrict__ cls,
                           float* __restrict__ h, unsigned short* __restrict__ hb) {
    int row = blockIdx.x;            // 0..16447
    int f = threadIdx.x;             // 256
    int g = row / S_LEN, s = row % S_LEN;
    float v = (s == 0) ? cls[f] : emb[((size_t)g * NPG + (s - 1)) * E_DIM + f];
    h[(size_t)row * E_DIM + f] = v;
    hb[(size_t)row * E_DIM + f] = f2b1(v);
}

// ---------------- MFMA flash attention: one workgroup per (graph, head) ------------
__global__ __launch_bounds__(256) void attn_mfma(const unsigned short* __restrict__ qkvb,
                                                 unsigned short* __restrict__ ob) {
    const int g  = blockIdx.x >> 3;
    const int hh = blockIdx.x & 7;
    __shared__ __align__(16) unsigned short Ks[272 * 32];      // K [s][d]
    __shared__ __align__(16) unsigned short VT[32 * 288];      // V^T [d][s]
    __shared__ __align__(16) unsigned short Ps[4 * 16 * 288];  // per-wave P tile
    const int tid  = threadIdx.x;
    const int wave = tid >> 6;
    const int lane = tid & 63;
    const int quad = lane >> 4;
    const int l16  = lane & 15;
    const size_t grow0 = (size_t)g * S_LEN;

    for (int s = tid; s < 272; s += 256) {
        uint4* dst = (uint4*)&Ks[s * 32];
        if (s < S_LEN) {
            const uint4* src = (const uint4*)(qkvb + (grow0 + s) * 768 + 256 + hh * 32);
            dst[0] = src[0]; dst[1] = src[1]; dst[2] = src[2]; dst[3] = src[3];
        } else {
            uint4 z = {0u, 0u, 0u, 0u};
            dst[0] = z; dst[1] = z; dst[2] = z; dst[3] = z;
        }
    }
    for (int s = tid; s < 288; s += 256) {
        unsigned short t[32];
        if (s < S_LEN) {
            const uint4* src = (const uint4*)(qkvb + (grow0 + s) * 768 + 512 + hh * 32);
            ((uint4*)t)[0] = src[0]; ((uint4*)t)[1] = src[1];
            ((uint4*)t)[2] = src[2]; ((uint4*)t)[3] = src[3];
        } else {
#pragma unroll
            for (int d = 0; d < 32; ++d) t[d] = 0;
        }
#pragma unroll
        for (int d = 0; d < 32; ++d) VT[d * 288 + s] = t[d];
    }
    unsigned short* Pw = &Ps[wave * 16 * 288];
    for (int i = lane; i < 256; i += 64)
        Pw[(i >> 4) * 288 + 272 + (i & 15)] = 0;
    __syncthreads();

    const float scale = 0.17677669529663687f;  // 1/sqrt(32)
    for (int qt = wave; qt < 17; qt += 4) {
        const int qrow_l = qt * 16 + l16;
        bf16x8 aq = *(const bf16x8*)(qkvb + (grow0 + qrow_l) * 768 + hh * 32 + quad * 8);

        f32x4 sc[17];
#pragma unroll
        for (int kt = 0; kt < 17; ++kt) {
            bf16x8 bk = *(const bf16x8*)&Ks[(kt * 16 + l16) * 32 + quad * 8];
            f32x4 z = (f32x4){0.f, 0.f, 0.f, 0.f};
            sc[kt] = __builtin_amdgcn_mfma_f32_16x16x32_bf16(aq, bk, z, 0, 0, 0);
        }

        float lsum[4] = {0.f, 0.f, 0.f, 0.f};
#pragma unroll
        for (int kt = 0; kt < 17; ++kt) {
#pragma unroll
            for (int r = 0; r < 4; ++r) {
                float p = __expf(sc[kt][r] * scale);
                if (kt == 16 && l16 != 0) p = 0.f;
                lsum[r] += p;
                Pw[(quad * 4 + r) * 288 + kt * 16 + l16] = f2b1(p);
            }
        }
#pragma unroll
        for (int r = 0; r < 4; ++r) {
            float s = lsum[r];
            s += __shfl_xor(s, 1, 64);
            s += __shfl_xor(s, 2, 64);
            s += __shfl_xor(s, 4, 64);
            s += __shfl_xor(s, 8, 64);
            lsum[r] = s;
        }

        f32x4 o0 = (f32x4){0.f, 0.f, 0.f, 0.f};
        f32x4 o1 = (f32x4){0.f, 0.f, 0.f, 0.f};
#pragma unroll
        for (int c = 0; c < 9; ++c) {
            bf16x8 ap  = *(const bf16x8*)&Pw[l16 * 288 + c * 32 + quad * 8];
            bf16x8 bv0 = *(const bf16x8*)&VT[l16 * 288 + c * 32 + quad * 8];
            bf16x8 bv1 = *(const bf16x8*)&VT[(16 + l16) * 288 + c * 32 + quad * 8];
            o0 = __builtin_amdgcn_mfma_f32_16x16x32_bf16(ap, bv0, o0, 0, 0, 0);
            o1 = __builtin_amdgcn_mfma_f32_16x16x32_bf16(ap, bv1, o1, 0, 0, 0);
        }

#pragma unroll
        for (int r = 0; r < 4; ++r) {
            int row_l = qt * 16 + quad * 4 + r;
            if (row_l < S_LEN) {
                float inv = 1.f / lsum[r];
                size_t orow = (grow0 + row_l) * E_DIM + hh * 32;
                ob[orow + l16]      = f2b1(o0[r] * inv);
                ob[orow + 16 + l16] = f2b1(o1[r] * inv);
            }
        }
    }
}

// ---------------- final classifier ----------------
__global__ void fc_kernel(const float* __restrict__ h, const float* __restrict__ w,
                          const float* __restrict__ b, float* __restrict__ out) {
    int g = blockIdx.x;
    __shared__ float row[E_DIM];
    int t = threadIdx.x;
    row[t] = h[(size_t)g * S_LEN * E_DIM + t];
    __syncthreads();
    if (t < N_CLASSES) {
        float s = 0.f;
        for (int j = 0; j < E_DIM; ++j) s += row[j] * w[t * E_DIM + j];
        out[g * N_CLASSES + t] = s + b[t];
    }
}

extern "C" void kernel_launch(void* const* d_in, const int* in_sizes, int n_in,
                              void* d_out, int out_size, void* d_ws, size_t ws_size,
                              hipStream_t stream) {
    const float* x       = (const float*)d_in[0];
    const int*   edgei   = (const int*)  d_in[1];
    const float* pos_enc = (const float*)d_in[3];
    const float* gcn_w   = (const float*)d_in[4];
    const float* gcn_b   = (const float*)d_in[5];
    const float* cls     = (const float*)d_in[6];
    const float* emb_w   = (const float*)d_in[7];
    const float* emb_b   = (const float*)d_in[8];
    const float* in_w    = (const float*)d_in[9];
    const float* in_b    = (const float*)d_in[10];
    const float* out_w   = (const float*)d_in[11];
    const float* out_b   = (const float*)d_in[12];
    const float* lin1_w  = (const float*)d_in[13];
    const float* lin1_b  = (const float*)d_in[14];
    const float* lin2_w  = (const float*)d_in[15];
    const float* lin2_b  = (const float*)d_in[16];
    const float* ln1_g   = (const float*)d_in[17];
    const float* ln1_be  = (const float*)d_in[18];
    const float* ln2_g   = (const float*)d_in[19];
    const float* ln2_be  = (const float*)d_in[20];
    const float* fc_w    = (const float*)d_in[21];
    const float* fc_b    = (const float*)d_in[22];
    float* out = (float*)d_out;

    // ---- workspace layout ----
    float* ws = (float*)d_ws;
    float* h    = ws;                                  // M_PAD*256 fp32
    float* qkv  = h   + (size_t)M_PAD * E_DIM;         // M_PAD*768 fp32 region
    float* xw   = qkv + (size_t)M_PAD * 768;           // 16384*128 fp32
    float* deg  = xw  + (size_t)N_NODES * F_IN;        // 16384 f
    int*   cursor    = (int*)(deg + N_NODES);          // 16384 i (zeroed with deg)
    int*   row_start = cursor + N_NODES;               // 16385 i
    int*   esrc      = row_start + N_NODES + 1;        // 262144 i
    float* enrm      = (float*)(esrc + N_EDGES);       // 262144 f
    unsigned short* ub     = (unsigned short*)(enrm + N_EDGES);
    unsigned short* hb     = ub;                                  // M_PAD*256
    unsigned short* attnob = hb     + (size_t)M_PAD * E_DIM;      // M_PAD*256
    unsigned short* fbufb  = attnob + (size_t)M_PAD * E_DIM;      // M_PAD*1024
    unsigned short* xb     = fbufb  + (size_t)M_PAD * MLP;        // 16384*128
    unsigned short* aggb   = xb     + (size_t)N_NODES * F_IN;     // 16384*128
    unsigned short* gcn_wb = aggb   + (size_t)N_NODES * F_IN;     // 128*128
    unsigned short* emb_wb = gcn_wb + (size_t)F_IN * F_IN;        // 256*128
    unsigned short* in_wb  = emb_wb + (size_t)E_DIM * F_IN;       // 4*768*256
    unsigned short* out_wb = in_wb  + (size_t)N_LAYERS * 768 * E_DIM;
    unsigned short* lin1_wb= out_wb + (size_t)N_LAYERS * E_DIM * E_DIM;
    unsigned short* lin2_wb= lin1_wb+ (size_t)N_LAYERS * MLP * E_DIM;
    float* emb_out = qkv;                        // alias (pre-loop)
    unsigned short* qkvb = (unsigned short*)qkv; // alias (in-loop, bf16)

    // ---- all weight/input conversions in one dispatch ----
    F2BJobs jobs;
    jobs.src[0] = x;      jobs.dst[0] = xb;      jobs.n4[0] = N_NODES * F_IN / 4;
    jobs.src[1] = gcn_w;  jobs.dst[1] = gcn_wb;  jobs.n4[1] = F_IN * F_IN / 4;
    jobs.src[2] = emb_w;  jobs.dst[2] = emb_wb;  jobs.n4[2] = E_DIM * F_IN / 4;
    jobs.src[3] = in_w;   jobs.dst[3] = in_wb;   jobs.n4[3] = N_LAYERS * 768 * E_DIM / 4;
    jobs.src[4] = out_w;  jobs.dst[4] = out_wb;  jobs.n4[4] = N_LAYERS * E_DIM * E_DIM / 4;
    jobs.src[5] = lin1_w; jobs.dst[5] = lin1_wb; jobs.n4[5] = N_LAYERS * MLP * E_DIM / 4;
    jobs.src[6] = lin2_w; jobs.dst[6] = lin2_wb; jobs.n4[6] = N_LAYERS * E_DIM * MLP / 4;
    f2b_all<<<1024, 256, 0, stream>>>(jobs);

    // ---- GCN: CSR build + gemm + gather ----
    hipMemsetAsync(deg, 0, 2 * N_NODES * sizeof(float), stream);  // deg + cursor
    deg_count<<<(N_EDGES + 255) / 256, 256, 0, stream>>>(edgei, deg);
    scan_deg<<<1, 1024, 0, stream>>>(deg, row_start);
    make_dinv<<<(N_NODES + 255) / 256, 256, 0, stream>>>(deg);
    gemm_mfma<<<dim3(F_IN / 128, N_NODES / 128), 256, 0, stream>>>(
        xb, gcn_wb, nullptr, nullptr, xw, nullptr, N_NODES, F_IN, F_IN, 0);
    scatter_edges<<<(N_EDGES + 255) / 256, 256, 0, stream>>>(edgei, deg, row_start, cursor, esrc, enrm);
    gcn_gather<<<N_NODES / 4, 256, 0, stream>>>(xw, row_start, esrc, enrm, deg, gcn_b, aggb);

    // ---- embedding + pos_enc ----
    gemm_mfma<<<dim3(E_DIM / 128, N_NODES / 128), 256, 0, stream>>>(
        aggb, emb_wb, emb_b, pos_enc, emb_out, nullptr, N_NODES, E_DIM, F_IN, 0);
    assemble_h<<<M_ROWS, E_DIM, 0, stream>>>(emb_out, cls, h, hb);

    // ---- transformer layers ----
    for (int l = 0; l < N_LAYERS; ++l) {
        gemm_mfma<<<dim3(768 / 128, M_PAD / 128), 256, 0, stream>>>(
            hb, in_wb + (size_t)l * 768 * E_DIM, in_b + (size_t)l * 768, nullptr,
            nullptr, qkvb, M_PAD, 768, E_DIM, 0);
        attn_mfma<<<N_GRAPHS * N_HEADS, 256, 0, stream>>>(qkvb, attnob);
        gemm_ln_t<E_DIM><<<M_PAD / 32, 256, 0, stream>>>(
            attnob, out_wb + (size_t)l * E_DIM * E_DIM, out_b + (size_t)l * E_DIM,
            ln1_g + l * E_DIM, ln1_be + l * E_DIM, h, hb);
        gemm_mfma<<<dim3(MLP / 128, M_PAD / 128), 256, 0, stream>>>(
            hb, lin1_wb + (size_t)l * MLP * E_DIM, lin1_b + (size_t)l * MLP, nullptr,
            nullptr, fbufb, M_PAD, MLP, E_DIM, 1);
        gemm_ln_t<MLP><<<M_PAD / 32, 256, 0, stream>>>(
            fbufb, lin2_wb + (size_t)l * MLP * E_DIM, lin2_b + (size_t)l * E_DIM,
            ln2_g + l * E_DIM, ln2_be + l * E_DIM, h, hb);
    }

    // ---- classifier on cls tokens ----
    fc_kernel<<<N_GRAPHS, E_DIM, 0, stream>>>(h, fc_w, fc_b, out);
}